// Round 1
// baseline (309.113 us; speedup 1.0000x reference)
//
#include <hip/hip_runtime.h>
#include <hip/hip_bf16.h>
#include <math.h>

#define NSEQ 2048
#define DMODEL 256

typedef __attribute__((ext_vector_type(8))) __bf16 bf16x8;
typedef __attribute__((ext_vector_type(4))) float f32x4;
typedef __attribute__((ext_vector_type(8))) unsigned short ushort8;
typedef __attribute__((ext_vector_type(4))) unsigned int uint4e;

__device__ __forceinline__ unsigned short f2b(float f) {
    return __builtin_bit_cast(unsigned short, (__bf16)f);
}
__device__ __forceinline__ bf16x8 ldfrag16(const void* p) {
    return __builtin_bit_cast(bf16x8, *(const uint4e*)p);
}

// ---------------- LayerNorm: 1 wave per row of 256, fp32 in -> bf16 out ----
__global__ __launch_bounds__(256)
void ln_kernel(const float* __restrict__ x, const float* __restrict__ g,
               const float* __restrict__ b, __bf16* __restrict__ out)
{
    const int row  = blockIdx.x * 4 + (threadIdx.x >> 6);
    const int lane = threadIdx.x & 63;
    const float4 v = *(const float4*)(x + (size_t)row * DMODEL + lane * 4);
    float s  = v.x + v.y + v.z + v.w;
    float s2 = v.x*v.x + v.y*v.y + v.z*v.z + v.w*v.w;
#pragma unroll
    for (int off = 32; off; off >>= 1) {
        s  += __shfl_xor(s, off);
        s2 += __shfl_xor(s2, off);
    }
    const float mu = s * (1.0f / DMODEL);
    const float rs = rsqrtf(s2 * (1.0f / DMODEL) - mu * mu + 1e-5f);
    const float4 gv = *(const float4*)(g + lane * 4);
    const float4 bv = *(const float4*)(b + lane * 4);
    __bf16* o = out + (size_t)row * DMODEL + lane * 4;
    o[0] = (__bf16)((v.x - mu) * rs * gv.x + bv.x);
    o[1] = (__bf16)((v.y - mu) * rs * gv.y + bv.y);
    o[2] = (__bf16)((v.z - mu) * rs * gv.z + bv.z);
    o[3] = (__bf16)((v.w - mu) * rs * gv.w + bv.w);
}

// ---------------- GEMM: C = epi(A[M,K]bf16 @ W[K,N]f32 + bias) -------------
// EPI 0: -> bf16. EPI 1: exact GELU -> bf16. EPI 2: + resid -> f32.
// 64x64 tile, BK=32, 4 waves each computing a 32x32 quadrant via 16x16x32 MFMA.
template<int EPI>
__global__ __launch_bounds__(256)
void gemm_kernel(const __bf16* __restrict__ A, const float* __restrict__ W,
                 const float* __restrict__ bias, const float* __restrict__ resid,
                 void* __restrict__ outp, int M, int N, int K)
{
    __shared__ short As[64][40];   // [row][k], padded to 40 for 16B-aligned frag reads
    __shared__ short Bs[64][40];   // [col][k] (W transposed), padded

    const int t    = threadIdx.x;
    const int lane = t & 63;
    const int w    = t >> 6;
    const int wr   = w >> 1, wc = w & 1;
    const int g    = lane >> 4, c = lane & 15;
    const int row0 = blockIdx.y * 64;
    const int col0 = blockIdx.x * 64;

    f32x4 acc[2][2] = {};

    const int ar = t >> 2, ac = (t & 3) * 8;      // A staging: 64 rows x 32 k
    const int bj = t & 63, bk = (t >> 6) * 8;     // B staging: 64 cols x 32 k

    for (int kt = 0; kt < K; kt += 32) {
        *(uint4e*)&As[ar][ac] = *(const uint4e*)(A + (size_t)(row0 + ar) * K + kt + ac);
        {
            const float* wp = W + (size_t)(kt + bk) * N + col0 + bj;
            const float f0 = wp[0];             const float f1 = wp[(size_t)N];
            const float f2 = wp[(size_t)2 * N]; const float f3 = wp[(size_t)3 * N];
            const float f4 = wp[(size_t)4 * N]; const float f5 = wp[(size_t)5 * N];
            const float f6 = wp[(size_t)6 * N]; const float f7 = wp[(size_t)7 * N];
            uint4e uu;
            uu.x = (unsigned)f2b(f0) | ((unsigned)f2b(f1) << 16);
            uu.y = (unsigned)f2b(f2) | ((unsigned)f2b(f3) << 16);
            uu.z = (unsigned)f2b(f4) | ((unsigned)f2b(f5) << 16);
            uu.w = (unsigned)f2b(f6) | ((unsigned)f2b(f7) << 16);
            *(uint4e*)&Bs[bj][bk] = uu;
        }
        __syncthreads();
        const bf16x8 a0 = ldfrag16(&As[wr * 32 +  0 + c][g * 8]);
        const bf16x8 a1 = ldfrag16(&As[wr * 32 + 16 + c][g * 8]);
        const bf16x8 b0 = ldfrag16(&Bs[wc * 32 +  0 + c][g * 8]);
        const bf16x8 b1 = ldfrag16(&Bs[wc * 32 + 16 + c][g * 8]);
        acc[0][0] = __builtin_amdgcn_mfma_f32_16x16x32_bf16(a0, b0, acc[0][0], 0, 0, 0);
        acc[0][1] = __builtin_amdgcn_mfma_f32_16x16x32_bf16(a0, b1, acc[0][1], 0, 0, 0);
        acc[1][0] = __builtin_amdgcn_mfma_f32_16x16x32_bf16(a1, b0, acc[1][0], 0, 0, 0);
        acc[1][1] = __builtin_amdgcn_mfma_f32_16x16x32_bf16(a1, b1, acc[1][1], 0, 0, 0);
        __syncthreads();
    }

#pragma unroll
    for (int rh = 0; rh < 2; ++rh)
#pragma unroll
    for (int ch = 0; ch < 2; ++ch)
#pragma unroll
    for (int r = 0; r < 4; ++r) {
        const int row = row0 + wr * 32 + rh * 16 + g * 4 + r;
        const int col = col0 + wc * 32 + ch * 16 + c;
        float val = acc[rh][ch][r] + bias[col];
        if (EPI == 0) {
            ((__bf16*)outp)[(size_t)row * N + col] = (__bf16)val;
        } else if (EPI == 1) {
            val = 0.5f * val * (1.0f + erff(val * 0.70710678118654752f));
            ((__bf16*)outp)[(size_t)row * N + col] = (__bf16)val;
        } else {
            ((float*)outp)[(size_t)row * N + col] = resid[(size_t)row * N + col] + val;
        }
    }
}

// ---------------- Flash attention, all 8 heads per block --------------------
// Block: 512 threads = 8 waves, wave w owns head w, 16 Q-rows per block.
// Influence tile read once per (b, n-tile, m-tile) and shared across heads.
// Double-buffered V/influence staging with reg-prefetch (single barrier/step).
__global__ __launch_bounds__(512)
void attn_kernel(const __bf16* __restrict__ Q, const __bf16* __restrict__ K,
                 const __bf16* __restrict__ V, const float* __restrict__ infl,
                 __bf16* __restrict__ O)
{
    __shared__ float ilds[2][16][33];    // influence tile (16 q-rows x 32 m)
    __shared__ short Vt[2][256][40];     // V transposed: [d][m], padded
    __shared__ short Plds[8][16][40];    // per-wave P round-trip (D-layout -> A-layout)

    const int t    = threadIdx.x;
    const int lane = t & 63;
    const int w    = t >> 6;             // head index
    const int g    = lane >> 4, c = lane & 15;
    const int b    = blockIdx.y;
    const int n0   = blockIdx.x * 16;

    // Q fragment (A operand): row = c, k within head = g*8+e. Direct 16B load.
    const bf16x8 qf = ldfrag16(Q + (size_t)(b * NSEQ + n0 + c) * DMODEL + w * 32 + g * 8);

    f32x4 Oacc[2] = {};
    float mrun[4] = {-1e30f, -1e30f, -1e30f, -1e30f};
    float lrun[4] = {0.f, 0.f, 0.f, 0.f};
    const float scale = 0.17677669529663687f;   // 1/sqrt(32)

    // staging assignments
    const int ir = t >> 5, im = t & 31;          // influence: 16x32 floats
    const int vdg = t >> 4, vmp = (t & 15) * 2;  // V: 32 d-groups x 16 m-pairs

    const float*  ibase = infl + (size_t)(b * NSEQ + n0 + ir) * NSEQ + im;
    const __bf16* vbase = V + (size_t)(b * NSEQ + vmp) * DMODEL + vdg * 8;

    // prologue: stage regs for m0 = 0
    float   iv  = ibase[0];
    ushort8 va0 = *(const ushort8*)(vbase);
    ushort8 va1 = *(const ushort8*)(vbase + DMODEL);

    int buf = 0;
    for (int m0 = 0; m0 < NSEQ; m0 += 32) {
        // write staged regs to LDS[buf]
        ilds[buf][ir][im] = iv;
#pragma unroll
        for (int dd = 0; dd < 8; ++dd) {
            const unsigned int pk = (unsigned)va0[dd] | ((unsigned)va1[dd] << 16);
            *(unsigned int*)&Vt[buf][vdg * 8 + dd][vmp] = pk;
        }
        __syncthreads();

        // prefetch next tile (latency hidden under compute below)
        const int mn = (m0 + 32) & (NSEQ - 1);
        iv = ibase[mn];
        const __bf16* vb2 = vbase + (size_t)mn * DMODEL;
        va0 = *(const ushort8*)(vb2);
        va1 = *(const ushort8*)(vb2 + DMODEL);

        // QK^T: K fragments (B operand) straight from global, 16B row loads
        const __bf16* kb = K + (size_t)(b * NSEQ + m0 + c) * DMODEL + w * 32 + g * 8;
        const bf16x8 kf0 = ldfrag16(kb);
        const bf16x8 kf1 = ldfrag16(kb + (size_t)16 * DMODEL);
        f32x4 s0 = {0.f, 0.f, 0.f, 0.f};
        f32x4 s1 = {0.f, 0.f, 0.f, 0.f};
        s0 = __builtin_amdgcn_mfma_f32_16x16x32_bf16(qf, kf0, s0, 0, 0, 0);
        s1 = __builtin_amdgcn_mfma_f32_16x16x32_bf16(qf, kf1, s1, 0, 0, 0);

        // scores * scale * (1 + influence); online softmax (rows live in lane-group g)
        float p0[4], p1[4], pmax[4];
#pragma unroll
        for (int r = 0; r < 4; ++r) {
            const float w0 = scale * (1.0f + ilds[buf][g * 4 + r][c]);
            const float w1 = scale * (1.0f + ilds[buf][g * 4 + r][c + 16]);
            p0[r] = s0[r] * w0;
            p1[r] = s1[r] * w1;
            pmax[r] = fmaxf(p0[r], p1[r]);
        }
#pragma unroll
        for (int off = 8; off; off >>= 1)
#pragma unroll
            for (int r = 0; r < 4; ++r)
                pmax[r] = fmaxf(pmax[r], __shfl_xor(pmax[r], off));

        float corr[4], psum[4];
#pragma unroll
        for (int r = 0; r < 4; ++r) {
            const float nm = fmaxf(mrun[r], pmax[r]);
            corr[r] = __expf(mrun[r] - nm);
            mrun[r] = nm;
            p0[r] = __expf(p0[r] - nm);
            p1[r] = __expf(p1[r] - nm);
            psum[r] = p0[r] + p1[r];
        }
#pragma unroll
        for (int off = 8; off; off >>= 1)
#pragma unroll
            for (int r = 0; r < 4; ++r)
                psum[r] += __shfl_xor(psum[r], off);

#pragma unroll
        for (int r = 0; r < 4; ++r) {
            lrun[r] = lrun[r] * corr[r] + psum[r];
            Plds[w][g * 4 + r][c]      = (short)f2b(p0[r]);
            Plds[w][g * 4 + r][c + 16] = (short)f2b(p1[r]);
            Oacc[0][r] *= corr[r];
            Oacc[1][r] *= corr[r];
        }
        // compiler fence: Plds short-writes must precede the vector re-read below
        asm volatile("" ::: "memory");

        const bf16x8 pf  = ldfrag16(&Plds[w][c][g * 8]);
        const bf16x8 vf0 = ldfrag16(&Vt[buf][w * 32 +  0 + c][g * 8]);
        const bf16x8 vf1 = ldfrag16(&Vt[buf][w * 32 + 16 + c][g * 8]);
        Oacc[0] = __builtin_amdgcn_mfma_f32_16x16x32_bf16(pf, vf0, Oacc[0], 0, 0, 0);
        Oacc[1] = __builtin_amdgcn_mfma_f32_16x16x32_bf16(pf, vf1, Oacc[1], 0, 0, 0);

        buf ^= 1;
    }

    __bf16* ob = O + (size_t)(b * NSEQ + n0 + g * 4) * DMODEL + w * 32 + c;
#pragma unroll
    for (int dh = 0; dh < 2; ++dh)
#pragma unroll
        for (int r = 0; r < 4; ++r)
            ob[(size_t)r * DMODEL + dh * 16] = (__bf16)(Oacc[dh][r] / lrun[r]);
}

// ---------------------------------------------------------------------------
extern "C" void kernel_launch(void* const* d_in, const int* in_sizes, int n_in,
                              void* d_out, int out_size, void* d_ws, size_t ws_size,
                              hipStream_t stream)
{
    (void)in_sizes; (void)n_in; (void)out_size; (void)ws_size;
    const float* x    = (const float*)d_in[0];
    const float* infl = (const float*)d_in[1];
    const float* qw   = (const float*)d_in[2];
    const float* qb   = (const float*)d_in[3];
    const float* kw   = (const float*)d_in[4];
    const float* kb   = (const float*)d_in[5];
    const float* vw   = (const float*)d_in[6];
    const float* vb   = (const float*)d_in[7];
    const float* ow   = (const float*)d_in[8];
    const float* ob   = (const float*)d_in[9];
    const float* w1   = (const float*)d_in[10];
    const float* b1   = (const float*)d_in[11];
    const float* w2   = (const float*)d_in[12];
    const float* b2   = (const float*)d_in[13];
    const float* ln1w = (const float*)d_in[14];
    const float* ln1b = (const float*)d_in[15];
    const float* ln2w = (const float*)d_in[16];
    const float* ln2b = (const float*)d_in[17];
    float* out = (float*)d_out;

    char* ws = (char*)d_ws;
    __bf16* h   = (__bf16*)(ws +  0 * 1048576ull);   // 2 MB  LN1 out
    __bf16* q   = (__bf16*)(ws +  2 * 1048576ull);   // 2 MB
    __bf16* kx  = (__bf16*)(ws +  4 * 1048576ull);   // 2 MB
    __bf16* vx  = (__bf16*)(ws +  6 * 1048576ull);   // 2 MB
    __bf16* ao  = (__bf16*)(ws +  8 * 1048576ull);   // 2 MB  attention out
    float*  x2  = (float*) (ws + 10 * 1048576ull);   // 4 MB  residual 1 (fp32)
    __bf16* h2  = (__bf16*)(ws + 14 * 1048576ull);   // 2 MB  LN2 out
    __bf16* ff  = (__bf16*)(ws + 16 * 1048576ull);   // 8 MB  FFN hidden

    ln_kernel<<<1024, 256, 0, stream>>>(x, ln1w, ln1b, h);
    gemm_kernel<0><<<dim3(4, 64),  256, 0, stream>>>(h,  qw, qb, nullptr, q,   4096,  256,  256);
    gemm_kernel<0><<<dim3(4, 64),  256, 0, stream>>>(h,  kw, kb, nullptr, kx,  4096,  256,  256);
    gemm_kernel<0><<<dim3(4, 64),  256, 0, stream>>>(h,  vw, vb, nullptr, vx,  4096,  256,  256);
    attn_kernel<<<dim3(128, 2),    512, 0, stream>>>(q, kx, vx, infl, ao);
    gemm_kernel<2><<<dim3(4, 64),  256, 0, stream>>>(ao, ow, ob, x,      x2,  4096,  256,  256);
    ln_kernel<<<1024, 256, 0, stream>>>(x2, ln2w, ln2b, h2);
    gemm_kernel<1><<<dim3(16, 64), 256, 0, stream>>>(h2, w1, b1, nullptr, ff,  4096, 1024,  256);
    gemm_kernel<2><<<dim3(4, 64),  256, 0, stream>>>(ff, w2, b2, x2,     out, 4096,  256, 1024);
}

// Round 2
// 231.244 us; speedup vs baseline: 1.3367x; 1.3367x over previous
//
#include <hip/hip_runtime.h>
#include <hip/hip_bf16.h>
#include <math.h>

#define NSEQ 2048
#define DMODEL 256

typedef __attribute__((ext_vector_type(8))) __bf16 bf16x8;
typedef __attribute__((ext_vector_type(4))) float f32x4;
typedef __attribute__((ext_vector_type(8))) unsigned short ushort8;
typedef __attribute__((ext_vector_type(4))) unsigned int uint4e;

__device__ __forceinline__ unsigned short f2b(float f) {
    return __builtin_bit_cast(unsigned short, (__bf16)f);
}
__device__ __forceinline__ float b2f(unsigned short u) {
    return (float)__builtin_bit_cast(__bf16, u);
}
__device__ __forceinline__ bf16x8 ldfrag16(const void* p) {
    return __builtin_bit_cast(bf16x8, *(const uint4e*)p);
}

// ---------------- LayerNorm: 1 wave per row of 256, fp32 in -> bf16 out ----
__global__ __launch_bounds__(256)
void ln_kernel(const float* __restrict__ x, const float* __restrict__ g,
               const float* __restrict__ b, __bf16* __restrict__ out)
{
    const int row  = blockIdx.x * 4 + (threadIdx.x >> 6);
    const int lane = threadIdx.x & 63;
    const float4 v = *(const float4*)(x + (size_t)row * DMODEL + lane * 4);
    float s  = v.x + v.y + v.z + v.w;
    float s2 = v.x*v.x + v.y*v.y + v.z*v.z + v.w*v.w;
#pragma unroll
    for (int off = 32; off; off >>= 1) {
        s  += __shfl_xor(s, off);
        s2 += __shfl_xor(s2, off);
    }
    const float mu = s * (1.0f / DMODEL);
    const float rs = rsqrtf(s2 * (1.0f / DMODEL) - mu * mu + 1e-5f);
    const float4 gv = *(const float4*)(g + lane * 4);
    const float4 bv = *(const float4*)(b + lane * 4);
    __bf16* o = out + (size_t)row * DMODEL + lane * 4;
    o[0] = (__bf16)((v.x - mu) * rs * gv.x + bv.x);
    o[1] = (__bf16)((v.y - mu) * rs * gv.y + bv.y);
    o[2] = (__bf16)((v.z - mu) * rs * gv.z + bv.z);
    o[3] = (__bf16)((v.w - mu) * rs * gv.w + bv.w);
}

// ---------------- GEMM core: C = epi(A[M,K]bf16 @ W[K,N]f32 + bias) --------
// EPI 0: -> bf16. EPI 1: exact GELU -> bf16. EPI 2: + resid -> f32.
// EPI 3: -> bf16 TRANSPOSED output (out[N][M]) via LDS transpose epilogue.
// 64x64 tile, BK=32, double-buffered LDS, reg prefetch, 1 barrier per K-step.
__device__ __forceinline__ void gemm_core(
    const __bf16* __restrict__ A, const float* __restrict__ W,
    const float* __restrict__ bias, const float* __restrict__ resid,
    void* __restrict__ outp, int M, int N, int K, int epi, short* smem)
{
    const int t    = threadIdx.x;
    const int lane = t & 63;
    const int w    = t >> 6;
    const int wr   = w >> 1, wc = w & 1;
    const int g    = lane >> 4, c = lane & 15;
    const int row0 = blockIdx.y * 64;
    const int col0 = blockIdx.x * 64;

    f32x4 acc[2][2] = {};

    const int ar  = t >> 2, ac2 = (t & 3) * 8;    // A staging: 64 rows x 32 k
    const int bj  = t & 63, bk  = (t >> 6) * 8;   // B staging: 64 cols x 32 k

    const __bf16* aptr = A + (size_t)(row0 + ar) * K + ac2;
    const float*  wptr = W + (size_t)bk * N + col0 + bj;

    uint4e areg = *(const uint4e*)aptr;
    float f0 = wptr[0];
    float f1 = wptr[(size_t)N];
    float f2 = wptr[(size_t)2 * N];
    float f3 = wptr[(size_t)3 * N];
    float f4 = wptr[(size_t)4 * N];
    float f5 = wptr[(size_t)5 * N];
    float f6 = wptr[(size_t)6 * N];
    float f7 = wptr[(size_t)7 * N];

    int buf = 0;
    for (int kt = 0; kt < K; kt += 32) {
        *(uint4e*)(smem + buf * 2560 + ar * 40 + ac2) = areg;
        {
            uint4e uu;
            uu.x = (unsigned)f2b(f0) | ((unsigned)f2b(f1) << 16);
            uu.y = (unsigned)f2b(f2) | ((unsigned)f2b(f3) << 16);
            uu.z = (unsigned)f2b(f4) | ((unsigned)f2b(f5) << 16);
            uu.w = (unsigned)f2b(f6) | ((unsigned)f2b(f7) << 16);
            *(uint4e*)(smem + 5120 + buf * 2560 + bj * 40 + bk) = uu;
        }
        __syncthreads();
        const int ktn = (kt + 32 < K) ? (kt + 32) : kt;   // prefetch next tile
        areg = *(const uint4e*)(aptr + ktn);
        {
            const float* wp2 = wptr + (size_t)ktn * N;
            f0 = wp2[0];             f1 = wp2[(size_t)N];
            f2 = wp2[(size_t)2 * N]; f3 = wp2[(size_t)3 * N];
            f4 = wp2[(size_t)4 * N]; f5 = wp2[(size_t)5 * N];
            f6 = wp2[(size_t)6 * N]; f7 = wp2[(size_t)7 * N];
        }
        const short* as = smem + buf * 2560;
        const short* bs = smem + 5120 + buf * 2560;
        const bf16x8 a0 = ldfrag16(as + (wr * 32 +      c) * 40 + g * 8);
        const bf16x8 a1 = ldfrag16(as + (wr * 32 + 16 + c) * 40 + g * 8);
        const bf16x8 b0 = ldfrag16(bs + (wc * 32 +      c) * 40 + g * 8);
        const bf16x8 b1 = ldfrag16(bs + (wc * 32 + 16 + c) * 40 + g * 8);
        acc[0][0] = __builtin_amdgcn_mfma_f32_16x16x32_bf16(a0, b0, acc[0][0], 0, 0, 0);
        acc[0][1] = __builtin_amdgcn_mfma_f32_16x16x32_bf16(a0, b1, acc[0][1], 0, 0, 0);
        acc[1][0] = __builtin_amdgcn_mfma_f32_16x16x32_bf16(a1, b0, acc[1][0], 0, 0, 0);
        acc[1][1] = __builtin_amdgcn_mfma_f32_16x16x32_bf16(a1, b1, acc[1][1], 0, 0, 0);
        buf ^= 1;
    }

    if (epi == 3) {
        // transposed epilogue: stage bf16 tile in LDS, write out[N][M] coalesced
        __syncthreads();
#pragma unroll
        for (int rh = 0; rh < 2; ++rh)
#pragma unroll
        for (int ch = 0; ch < 2; ++ch)
#pragma unroll
        for (int r = 0; r < 4; ++r) {
            const int rl = wr * 32 + rh * 16 + g * 4 + r;
            const int cl = wc * 32 + ch * 16 + c;
            smem[rl * 66 + cl] = (short)f2b(acc[rh][ch][r] + bias[col0 + cl]);
        }
        __syncthreads();
        const int d = t >> 2, mc = (t & 3) * 16;
        ushort8 o0, o1;
#pragma unroll
        for (int j = 0; j < 8; ++j) {
            o0[j] = (unsigned short)smem[(mc + j) * 66 + d];
            o1[j] = (unsigned short)smem[(mc + 8 + j) * 66 + d];
        }
        __bf16* vt = (__bf16*)outp;
        const size_t oa = (size_t)(col0 + d) * M + row0 + mc;
        *(uint4e*)(vt + oa)     = __builtin_bit_cast(uint4e, o0);
        *(uint4e*)(vt + oa + 8) = __builtin_bit_cast(uint4e, o1);
    } else {
#pragma unroll
        for (int rh = 0; rh < 2; ++rh)
#pragma unroll
        for (int ch = 0; ch < 2; ++ch)
#pragma unroll
        for (int r = 0; r < 4; ++r) {
            const int row = row0 + wr * 32 + rh * 16 + g * 4 + r;
            const int col = col0 + wc * 32 + ch * 16 + c;
            float val = acc[rh][ch][r] + bias[col];
            if (epi == 0) {
                ((__bf16*)outp)[(size_t)row * N + col] = (__bf16)val;
            } else if (epi == 1) {
                val = 0.5f * val * (1.0f + erff(val * 0.70710678118654752f));
                ((__bf16*)outp)[(size_t)row * N + col] = (__bf16)val;
            } else {
                ((float*)outp)[(size_t)row * N + col] = resid[(size_t)row * N + col] + val;
            }
        }
    }
}

template<int EPI>
__global__ __launch_bounds__(256)
void gemm_kernel(const __bf16* __restrict__ A, const float* __restrict__ W,
                 const float* __restrict__ bias, const float* __restrict__ resid,
                 void* __restrict__ outp, int M, int N, int K)
{
    __shared__ short smem[10240];
    gemm_core(A, W, bias, resid, outp, M, N, K, EPI, smem);
}

// fused QKV projection: blockIdx.z selects weight/bias/output; z=2 writes V^T
__global__ __launch_bounds__(256)
void qkv_kernel(const __bf16* __restrict__ A,
                const float* __restrict__ qw, const float* __restrict__ qb,
                const float* __restrict__ kw, const float* __restrict__ kb,
                const float* __restrict__ vw, const float* __restrict__ vb,
                __bf16* __restrict__ qo, __bf16* __restrict__ ko,
                __bf16* __restrict__ vto)
{
    __shared__ short smem[10240];
    const int z = blockIdx.z;
    const float* W    = (z == 0) ? qw : (z == 1) ? kw : vw;
    const float* bias = (z == 0) ? qb : (z == 1) ? kb : vb;
    void* outp        = (z == 0) ? (void*)qo : (z == 1) ? (void*)ko : (void*)vto;
    gemm_core(A, W, bias, nullptr, outp, 4096, 256, 256, (z == 2) ? 3 : 0, smem);
}

// ---------------- Flash attention, barrier-free main loop -------------------
// Grid (128 n-tiles, 2 KV-splits, 2 batch). Block: 8 waves, wave w = head w,
// 16 Q-rows, KVBLK=64. K/V^T/influence loaded straight from global with
// one-iteration register prefetch; only LDS use is the per-wave P transpose.
// Writes unnormalized partial O (bf16) + per-row (m, l) for the combine pass.
__global__ __launch_bounds__(512, 4)
void attn_kernel(const __bf16* __restrict__ Q, const __bf16* __restrict__ K,
                 const __bf16* __restrict__ VT, const float* __restrict__ infl,
                 __bf16* __restrict__ Opart, float* __restrict__ ml)
{
    __shared__ short Plds[8][16][72];

    const int t    = threadIdx.x;
    const int lane = t & 63;
    const int w    = t >> 6;             // head
    const int g    = lane >> 4, c = lane & 15;
    const int b    = blockIdx.z;
    const int sp   = blockIdx.y;
    const int n0   = blockIdx.x * 16;
    const int m_start = sp * 1024;

    const bf16x8 qf = ldfrag16(Q + (size_t)(b * NSEQ + n0 + c) * DMODEL + w * 32 + g * 8);

    const __bf16* Khead = K  + (size_t)(b * NSEQ + c) * DMODEL + w * 32 + g * 8;
    const __bf16* Vhead = VT + (size_t)(w * 32 + c) * (2 * NSEQ) + b * NSEQ + g * 8;
    const float*  irow  = infl + (size_t)(b * NSEQ + n0 + g * 4) * NSEQ + c;

    f32x4 Oacc[2] = {};
    float mrun[4] = {-1e30f, -1e30f, -1e30f, -1e30f};
    float lrun[4] = {0.f, 0.f, 0.f, 0.f};
    const float scale = 0.17677669529663687f;   // 1/sqrt(32)

    bf16x8 kf[4];
    float finf[4][4];
#pragma unroll
    for (int mt = 0; mt < 4; ++mt) {
        kf[mt] = ldfrag16(Khead + (size_t)(m_start + mt * 16) * DMODEL);
#pragma unroll
        for (int r = 0; r < 4; ++r)
            finf[mt][r] = irow[(size_t)r * NSEQ + m_start + mt * 16];
    }

    for (int it = 0; it < 16; ++it) {
        const int m0 = m_start + (it << 6);
        const int mn = m_start + (((it + 1) & 15) << 6);

        f32x4 s[4];
#pragma unroll
        for (int mt = 0; mt < 4; ++mt) {
            f32x4 z4 = {0.f, 0.f, 0.f, 0.f};
            s[mt] = __builtin_amdgcn_mfma_f32_16x16x32_bf16(qf, kf[mt], z4, 0, 0, 0);
        }
        // prefetch next K tile
#pragma unroll
        for (int mt = 0; mt < 4; ++mt)
            kf[mt] = ldfrag16(Khead + (size_t)(mn + mt * 16) * DMODEL);
        // current V^T fragments (used after softmax — latency covered)
        bf16x8 vfa[4];
#pragma unroll
        for (int ks = 0; ks < 2; ++ks)
#pragma unroll
            for (int dt = 0; dt < 2; ++dt)
                vfa[ks * 2 + dt] =
                    ldfrag16(Vhead + (size_t)(dt * 16) * (2 * NSEQ) + m0 + ks * 32);

        float p[4][4], pm[4];
#pragma unroll
        for (int r = 0; r < 4; ++r) {
#pragma unroll
            for (int mt = 0; mt < 4; ++mt)
                p[mt][r] = s[mt][r] * scale * (1.0f + finf[mt][r]);
            pm[r] = fmaxf(fmaxf(p[0][r], p[1][r]), fmaxf(p[2][r], p[3][r]));
        }
        // prefetch next influence fragment
#pragma unroll
        for (int mt = 0; mt < 4; ++mt)
#pragma unroll
            for (int r = 0; r < 4; ++r)
                finf[mt][r] = irow[(size_t)r * NSEQ + mn + mt * 16];

#pragma unroll
        for (int off = 8; off; off >>= 1)
#pragma unroll
            for (int r = 0; r < 4; ++r)
                pm[r] = fmaxf(pm[r], __shfl_xor(pm[r], off));

        float corr[4], psum[4];
#pragma unroll
        for (int r = 0; r < 4; ++r) {
            const float nm = fmaxf(mrun[r], pm[r]);
            corr[r] = __expf(mrun[r] - nm);
            mrun[r] = nm;
#pragma unroll
            for (int mt = 0; mt < 4; ++mt)
                p[mt][r] = __expf(p[mt][r] - nm);
            psum[r] = (p[0][r] + p[1][r]) + (p[2][r] + p[3][r]);
        }
#pragma unroll
        for (int off = 8; off; off >>= 1)
#pragma unroll
            for (int r = 0; r < 4; ++r)
                psum[r] += __shfl_xor(psum[r], off);

#pragma unroll
        for (int r = 0; r < 4; ++r) {
            lrun[r] = lrun[r] * corr[r] + psum[r];
#pragma unroll
            for (int mt = 0; mt < 4; ++mt)
                Plds[w][g * 4 + r][mt * 16 + c] = (short)f2b(p[mt][r]);
            Oacc[0][r] *= corr[r];
            Oacc[1][r] *= corr[r];
        }
        // compiler fence: Plds short-writes must precede the vector re-read
        asm volatile("" ::: "memory");

#pragma unroll
        for (int ks = 0; ks < 2; ++ks) {
            const bf16x8 pf = ldfrag16(&Plds[w][c][ks * 32 + g * 8]);
            Oacc[0] = __builtin_amdgcn_mfma_f32_16x16x32_bf16(pf, vfa[ks * 2 + 0], Oacc[0], 0, 0, 0);
            Oacc[1] = __builtin_amdgcn_mfma_f32_16x16x32_bf16(pf, vfa[ks * 2 + 1], Oacc[1], 0, 0, 0);
        }
    }

#pragma unroll
    for (int r = 0; r < 4; ++r) {
        const int grow = b * NSEQ + n0 + g * 4 + r;
        if (c == 0) {
            float* mp = ml + ((size_t)(sp * 4096 + grow) * 8 + w) * 2;
            mp[0] = mrun[r];
            mp[1] = lrun[r];
        }
#pragma unroll
        for (int dt = 0; dt < 2; ++dt)
            Opart[(size_t)(sp * 4096 + grow) * 256 + w * 32 + dt * 16 + c] =
                (__bf16)Oacc[dt][r];
    }
}

// ---------------- split-KV combine: ao = (w0*O0 + w1*O1) / (w0*l0 + w1*l1) --
__global__ __launch_bounds__(256)
void combine_kernel(const __bf16* __restrict__ Opart, const float* __restrict__ ml,
                    __bf16* __restrict__ ao)
{
    const int tid = blockIdx.x * 256 + threadIdx.x;
    const int row = tid >> 5;
    const int d0  = (tid & 31) * 8;
    const int h   = d0 >> 5;
    const float* m0p = ml + ((size_t)row * 8 + h) * 2;
    const float* m1p = ml + ((size_t)(4096 + row) * 8 + h) * 2;
    const float ma = m0p[0], la = m0p[1];
    const float mb = m1p[0], lb = m1p[1];
    const float M  = fmaxf(ma, mb);
    const float wa = __expf(ma - M), wb = __expf(mb - M);
    const float inv = 1.0f / (wa * la + wb * lb);
    const ushort8 xa = *(const ushort8*)(Opart + (size_t)row * 256 + d0);
    const ushort8 xb = *(const ushort8*)(Opart + (size_t)(4096 + row) * 256 + d0);
    __bf16 o[8];
#pragma unroll
    for (int e = 0; e < 8; ++e)
        o[e] = (__bf16)((wa * b2f(xa[e]) + wb * b2f(xb[e])) * inv);
    *(uint4e*)(ao + (size_t)row * 256 + d0) = *(uint4e*)o;
}

// ---------------------------------------------------------------------------
extern "C" void kernel_launch(void* const* d_in, const int* in_sizes, int n_in,
                              void* d_out, int out_size, void* d_ws, size_t ws_size,
                              hipStream_t stream)
{
    (void)in_sizes; (void)n_in; (void)out_size; (void)ws_size;
    const float* x    = (const float*)d_in[0];
    const float* infl = (const float*)d_in[1];
    const float* qw   = (const float*)d_in[2];
    const float* qb   = (const float*)d_in[3];
    const float* kw   = (const float*)d_in[4];
    const float* kb   = (const float*)d_in[5];
    const float* vw   = (const float*)d_in[6];
    const float* vb   = (const float*)d_in[7];
    const float* ow   = (const float*)d_in[8];
    const float* ob_  = (const float*)d_in[9];
    const float* w1   = (const float*)d_in[10];
    const float* b1   = (const float*)d_in[11];
    const float* w2   = (const float*)d_in[12];
    const float* b2   = (const float*)d_in[13];
    const float* ln1w = (const float*)d_in[14];
    const float* ln1b = (const float*)d_in[15];
    const float* ln2w = (const float*)d_in[16];
    const float* ln2b = (const float*)d_in[17];
    float* out = (float*)d_out;

    char* ws = (char*)d_ws;
    __bf16* h     = (__bf16*)(ws +  0 * 1048576ull);   // 2 MB  LN1 out
    __bf16* q     = (__bf16*)(ws +  2 * 1048576ull);   // 2 MB
    __bf16* kx    = (__bf16*)(ws +  4 * 1048576ull);   // 2 MB
    __bf16* vt    = (__bf16*)(ws +  6 * 1048576ull);   // 2 MB  V^T [256][4096]
    __bf16* Opart = (__bf16*)(ws +  8 * 1048576ull);   // 4 MB  partial O (2 splits)
    float*  mlbuf = (float*) (ws + 12 * 1048576ull);   // 0.5MB (m,l) per split/row/head
    __bf16* ao    = (__bf16*)(ws + 13 * 1048576ull);   // 2 MB  attention out
    float*  x2    = (float*) (ws + 15 * 1048576ull);   // 4 MB  residual 1 (fp32)
    __bf16* h2    = (__bf16*)(ws + 19 * 1048576ull);   // 2 MB  LN2 out
    __bf16* ff    = (__bf16*)(ws + 21 * 1048576ull);   // 8 MB  FFN hidden

    ln_kernel<<<1024, 256, 0, stream>>>(x, ln1w, ln1b, h);
    qkv_kernel<<<dim3(4, 64, 3), 256, 0, stream>>>(h, qw, qb, kw, kb, vw, vb, q, kx, vt);
    attn_kernel<<<dim3(128, 2, 2), 512, 0, stream>>>(q, kx, vt, infl, Opart, mlbuf);
    combine_kernel<<<512, 256, 0, stream>>>(Opart, mlbuf, ao);
    gemm_kernel<2><<<dim3(4, 64),  256, 0, stream>>>(ao, ow, ob_, x,      x2,  4096,  256,  256);
    ln_kernel<<<1024, 256, 0, stream>>>(x2, ln2w, ln2b, h2);
    gemm_kernel<1><<<dim3(16, 64), 256, 0, stream>>>(h2, w1, b1, nullptr, ff,  4096, 1024,  256);
    gemm_kernel<2><<<dim3(4, 64),  256, 0, stream>>>(ff, w2, b2, x2,     out, 4096,  256, 1024);
}